// Round 14
// baseline (2033.941 us; speedup 1.0000x reference)
//
#include <hip/hip_runtime.h>
#include <stdint.h>

typedef unsigned long long u64;
typedef unsigned int u32;

#define NPTS    131072
#define NBATCH  16
#define NSAMP   1024
#define SUBS    16                 // blocks per batch
#define THREADS 256
#define PPT     32                 // points per thread

// Packed word: [ tag:10 (bits 49..58) | key:32 (17..48) | (131071-idx):17 (0..16) ]
// key = 0 for masked-out (cand == -1), else float_bits(val)+1 (monotone for val >= 0).
// Max of packed (same tag) == reference first-max argmax (smaller index wins ties).
//
// Layout = r9's proven one: per-batch 32 u64 at 1024B stride; parity p ->
// slots [p*16 .. p*16+15] (ONE 128B line per parity). One plain agent store
// per block per round; pollers validate the embedded tag (self-contained).
//
// r14 change vs r13: the 4-deep poll pipeline is moved to INLINE ASM with
// counted s_waitcnt vmcnt(3) (T3/T4 pattern; HIP-level attempt in r13 was
// compiler-collapsed to one RT per check -> neutral). Sampling granularity
// ~1100cy -> ~170cy, shrinking the per-round discovery lag and the
// across-16-blocks straggler convoy. Only wave 0 polls the LLC line (16
// coalesced requests/line, utilization < 0.4); waves 1-3 spin on an LDS
// word (it<<17)|widx -- single u32, self-validating, parity-buffered (no
// torn reads, r3 lesson). Rule-18 discipline: sched_barrier(0) after each
// waitcnt; final vmcnt(0) drain pins the in-flight registers.

__device__ __forceinline__ void st_agent(u64* p, u64 v) {
    __hip_atomic_store(p, v, __ATOMIC_RELAXED, __HIP_MEMORY_SCOPE_AGENT);
}

#define PLOAD(dst, addr) \
    asm volatile("global_load_dwordx2 %0, %1, off sc0 sc1" : "=v"(dst) : "v"(addr) : "memory")
#define PWAIT3() do { \
    asm volatile("s_waitcnt vmcnt(3)" ::: "memory"); \
    __builtin_amdgcn_sched_barrier(0); } while (0)

__global__ __launch_bounds__(THREADS, 1)
void fps_kernel(const float* __restrict__ x, float* __restrict__ y, u64* __restrict__ ws)
{
    const int bid   = blockIdx.x;
    const int batch = bid & (NBATCH - 1);
    const int sub   = bid >> 4;
    const int tid   = threadIdx.x;
    const int lane  = tid & 63;
    const int wv    = tid >> 6;

    const float* __restrict__ xb = x + (size_t)batch * (NPTS * 3);
    const int gbase = sub * 8192 + wv * 2048;

    // register-resident points + running min distance (static indexing only)
    float px_[PPT], py_[PPT], pz_[PPT], t_[PPT];
#pragma unroll
    for (int k = 0; k < PPT; ++k) {
        const int g = gbase + k * 64 + lane;
        const float a = xb[3 * g + 0];
        const float b = xb[3 * g + 1];
        const float c = xb[3 * g + 2];
        px_[k] = a; py_[k] = b; pz_[k] = c;
        // exactly as reference: ((a*a + b*b) + c*c), no FMA contraction
        const float mag = __fadd_rn(__fadd_rn(__fmul_rn(a, a), __fmul_rn(b, b)), __fmul_rn(c, c));
        t_[k] = (mag > 1e-3f) ? 1e10f : -1.0f;   // masked-out: cand == -1 forever
    }

    __shared__ u64 s_red[2][4];
    __shared__ u32 s_win[2];                    // (it<<17)|widx, parity-buffered
    if (tid == 0) { s_win[0] = 0; s_win[1] = 0; }

    u64* const slots = ws + (size_t)batch * 128;   // 1024B per batch (u64 units)

    float cpx = xb[0], cpy = xb[1], cpz = xb[2];   // first pick is always index 0
    if (sub == 0 && tid == 0) {
        float* yo = y + (size_t)batch * (NSAMP * 3);
        yo[0] = cpx; yo[1] = cpy; yo[2] = cpz;
    }

    for (int it = 1; it < NSAMP; ++it) {
        // ---- update temps against current point, thread-local argmax ----
        float bv = -2.0f;
        int   bk = 0;
#pragma unroll
        for (int k = 0; k < PPT; ++k) {
            const float dx = __fsub_rn(px_[k], cpx);
            const float dy = __fsub_rn(py_[k], cpy);
            const float dz = __fsub_rn(pz_[k], cpz);
            const float d  = __fadd_rn(__fadd_rn(__fmul_rn(dx, dx), __fmul_rn(dy, dy)),
                                       __fmul_rn(dz, dz));
            const float tn = fminf(t_[k], d);
            t_[k] = tn;
            if (tn > bv) { bv = tn; bk = k; }   // strict > keeps smallest k
        }
        const int gidx = gbase + bk * 64 + lane;
        const u32 key  = (bv < 0.0f) ? 0u : (__float_as_uint(bv) + 1u);
        u64 packed = ((u64)(u32)it << 49) | ((u64)key << 17) | (u32)(131071 - gidx);

        // ---- wave reduce (max of packed, first-max tiebreak) ----
#pragma unroll
        for (int off = 32; off; off >>= 1) {
            const u64 o = __shfl_xor(packed, off);
            if (o > packed) packed = o;
        }

        const int par = it & 1;
        if (lane == 0) s_red[par][wv] = packed;   // parity-buffered: no cross-round overwrite
        __syncthreads();                          // the ONLY barrier per round

        int widx;
        if (wv == 0) {
            if (lane == 0) {
                u64 blk = s_red[par][0];
                if (s_red[par][1] > blk) blk = s_red[par][1];
                if (s_red[par][2] > blk) blk = s_red[par][2];
                if (s_red[par][3] > blk) blk = s_red[par][3];
                st_agent(slots + par * SUBS + sub, blk);
            }
            // ---- asm-pipelined poll: 4 outstanding sc0sc1 loads, counted vmcnt(3),
            //      ~170cy sampling. 64 lanes read slot (lane&15) -> 1 coalesced
            //      128B request per load. ----
            const u32 tag = (u32)it;
            u64* const sp = slots + par * SUBS + (lane & 15);
            u64 a0, a1, a2, a3, v;
            __builtin_amdgcn_s_sleep(4);          // skip the certainly-stale window
            PLOAD(a0, sp); __builtin_amdgcn_s_sleep(2);
            PLOAD(a1, sp); __builtin_amdgcn_s_sleep(2);
            PLOAD(a2, sp); __builtin_amdgcn_s_sleep(2);
            PLOAD(a3, sp);
            for (;;) {
                PWAIT3();
                if (__all((int)((u32)(a0 >> 49) == tag))) { v = a0; break; }
                PLOAD(a0, sp); __builtin_amdgcn_s_sleep(2);
                PWAIT3();
                if (__all((int)((u32)(a1 >> 49) == tag))) { v = a1; break; }
                PLOAD(a1, sp); __builtin_amdgcn_s_sleep(2);
                PWAIT3();
                if (__all((int)((u32)(a2 >> 49) == tag))) { v = a2; break; }
                PLOAD(a2, sp); __builtin_amdgcn_s_sleep(2);
                PWAIT3();
                if (__all((int)((u32)(a3 >> 49) == tag))) { v = a3; break; }
                PLOAD(a3, sp); __builtin_amdgcn_s_sleep(2);
            }
            // drain pending loads; pin their registers until drained
            asm volatile("s_waitcnt vmcnt(0)"
                         :: "v"(a0), "v"(a1), "v"(a2), "v"(a3) : "memory");
            __builtin_amdgcn_sched_barrier(0);
            // ---- reduce metas within 16-lane groups (group 0 holds all 16) ----
#pragma unroll
            for (int off = 8; off; off >>= 1) {
                const u64 o = __shfl_xor(v, off);
                if (o > v) v = o;
            }
            const u64 win = __shfl(v, 0);
            widx = 131071 - (int)(win & 0x1FFFF);
            if (lane == 0)
                __hip_atomic_store(&s_win[par], ((u32)it << 17) | (u32)widx,
                                   __ATOMIC_RELAXED, __HIP_MEMORY_SCOPE_WORKGROUP);
        } else {
            // ---- waves 1-3: spin on the self-validating LDS word (no LLC traffic) ----
            u32 w;
            for (;;) {
                w = __hip_atomic_load(&s_win[par], __ATOMIC_RELAXED,
                                      __HIP_MEMORY_SCOPE_WORKGROUP);
                if ((w >> 17) == (u32)it) break;
                __builtin_amdgcn_s_sleep(1);
            }
            widx = (int)(w & 0x1FFFF);
        }

        // all lanes load the same 12B: wv0 warms the line, siblings hit L1
        cpx = xb[3 * widx + 0];
        cpy = xb[3 * widx + 1];
        cpz = xb[3 * widx + 2];
        if (sub == 0 && tid == 0) {
            float* yo = y + ((size_t)batch * NSAMP + it) * 3;
            yo[0] = cpx; yo[1] = cpy; yo[2] = cpz;
        }
    }
}

extern "C" void kernel_launch(void* const* d_in, const int* in_sizes, int n_in,
                              void* d_out, int out_size, void* d_ws, size_t ws_size,
                              hipStream_t stream) {
    const float* x = (const float*)d_in[0];
    float* y       = (float*)d_out;
    u64* ws        = (u64*)d_ws;   // 16 batches * 1024B = 16 KiB

    // zero all slot words every call (in-graph). Tags used are 1..1023; stale
    // content (zeros, 0xAA poison, previous replay's tags overwritten here)
    // can never spuriously satisfy a round's tag check.
    hipMemsetAsync(d_ws, 0, (size_t)(NBATCH * 1024), stream);

    void* args[] = { (void*)&x, (void*)&y, (void*)&ws };
    hipLaunchCooperativeKernel((void*)fps_kernel,
                               dim3(NBATCH * SUBS), dim3(THREADS),
                               args, 0, stream);
}

// Round 15
// 2027.706 us; speedup vs baseline: 1.0031x; 1.0031x over previous
//
#include <hip/hip_runtime.h>
#include <stdint.h>

typedef unsigned long long u64;
typedef unsigned int u32;
typedef __attribute__((ext_vector_type(2))) float f32x2;

#define NPTS    131072
#define NBATCH  16
#define NSAMP   1024
#define SUBS    16                 // blocks per batch
#define THREADS 256
#define PPT     32                 // points per thread
#define PPAIR   16                 // packed point-pairs per thread

// Packed word: [ tag:10 (bits 49..58) | key:32 (17..48) | (131071-idx):17 (0..16) ]
// key = 0 for masked-out (cand == -1), else float_bits(val)+1 (monotone for val >= 0).
// Max of packed (same tag) == reference first-max argmax (smaller index wins ties).
//
// Sync structure = r9 VERBATIM (best: 1919us). 14 rounds of evidence: transport
// scope (LLC vs XCD-L2), sampling rate (1100->170cy), publish path, line layout,
// RMW-combining -- all neutral or negative. This round attacks the only
// untouched critical-path term: COMPUTE. The distance update moves to packed
// fp32 (v_pk_add/mul_f32: per-component IEEE round-to-nearest, bit-identical to
// scalar v_add/v_mul, NO fusion) -> 8 ops per point-pair instead of 16.
// Tie-break preserved: pair components tested in ascending k with strict >.

__device__ __forceinline__ u64 ld_agent(const u64* p) {
    return __hip_atomic_load(p, __ATOMIC_RELAXED, __HIP_MEMORY_SCOPE_AGENT);
}
__device__ __forceinline__ void st_agent(u64* p, u64 v) {
    __hip_atomic_store(p, v, __ATOMIC_RELAXED, __HIP_MEMORY_SCOPE_AGENT);
}

// pure value ops (non-volatile: scheduler may move/CSE them freely)
#define PK_SUB(d, a, b) asm("v_pk_add_f32 %0, %1, %2 neg_lo:[0,1] neg_hi:[0,1]" \
                            : "=v"(d) : "v"(a), "v"(b))
#define PK_MUL(d, a, b) asm("v_pk_mul_f32 %0, %1, %2" : "=v"(d) : "v"(a), "v"(b))
#define PK_ADD(d, a, b) asm("v_pk_add_f32 %0, %1, %2" : "=v"(d) : "v"(a), "v"(b))

__global__ __launch_bounds__(THREADS, 1)
void fps_kernel(const float* __restrict__ x, float* __restrict__ y, u64* __restrict__ ws)
{
    const int bid   = blockIdx.x;
    const int batch = bid & (NBATCH - 1);
    const int sub   = bid >> 4;
    const int tid   = threadIdx.x;
    const int lane  = tid & 63;
    const int wv    = tid >> 6;

    const float* __restrict__ xb = x + (size_t)batch * (NPTS * 3);
    const int gbase = sub * 8192 + wv * 2048;

    // register-resident point pairs + running min distance (static indexing only)
    f32x2 pxv[PPAIR], pyv[PPAIR], pzv[PPAIR], tv[PPAIR];

#pragma unroll
    for (int j = 0; j < PPAIR; ++j) {
        f32x2 a, b, c, t;
#pragma unroll
        for (int h = 0; h < 2; ++h) {
            const int g = gbase + (2 * j + h) * 64 + lane;
            const float ax = xb[3 * g + 0];
            const float bx = xb[3 * g + 1];
            const float cx = xb[3 * g + 2];
            // exactly as reference: ((a*a + b*b) + c*c), no FMA contraction
            const float mag = __fadd_rn(__fadd_rn(__fmul_rn(ax, ax), __fmul_rn(bx, bx)),
                                        __fmul_rn(cx, cx));
            if (h == 0) { a.x = ax; b.x = bx; c.x = cx; t.x = (mag > 1e-3f) ? 1e10f : -1.0f; }
            else        { a.y = ax; b.y = bx; c.y = cx; t.y = (mag > 1e-3f) ? 1e10f : -1.0f; }
        }
        pxv[j] = a; pyv[j] = b; pzv[j] = c; tv[j] = t;   // masked-out: cand == -1 forever
    }

    __shared__ u64 s_red[2][4];

    u64* const slots = ws + (size_t)batch * 128;   // 1024B per batch (u64 units)

    float cpx = xb[0], cpy = xb[1], cpz = xb[2];   // first pick is always index 0
    if (sub == 0 && tid == 0) {
        float* yo = y + (size_t)batch * (NSAMP * 3);
        yo[0] = cpx; yo[1] = cpy; yo[2] = cpz;
    }

    for (int it = 1; it < NSAMP; ++it) {
        // ---- packed update of temps against current point, thread-local argmax ----
        const f32x2 cx2 = { cpx, cpx };
        const f32x2 cy2 = { cpy, cpy };
        const f32x2 cz2 = { cpz, cpz };
        float bv = -2.0f;
        int   bk = 0;
#pragma unroll
        for (int j = 0; j < PPAIR; ++j) {
            f32x2 dx, dy, dz, xx, yy, zz, s1, dd;
            PK_SUB(dx, pxv[j], cx2);
            PK_SUB(dy, pyv[j], cy2);
            PK_SUB(dz, pzv[j], cz2);
            PK_MUL(xx, dx, dx);
            PK_MUL(yy, dy, dy);
            PK_MUL(zz, dz, dz);
            PK_ADD(s1, xx, yy);               // (dx^2 + dy^2)
            PK_ADD(dd, s1, zz);               // ... + dz^2  (same order as reference)
            const float t0 = fminf(tv[j].x, dd.x);
            const float t1 = fminf(tv[j].y, dd.y);
            tv[j].x = t0;
            tv[j].y = t1;
            if (t0 > bv) { bv = t0; bk = 2 * j; }       // ascending k, strict >
            if (t1 > bv) { bv = t1; bk = 2 * j + 1; }   // => first-max preserved
        }
        const int gidx = gbase + bk * 64 + lane;
        const u32 key  = (bv < 0.0f) ? 0u : (__float_as_uint(bv) + 1u);
        u64 packed = ((u64)(u32)it << 49) | ((u64)key << 17) | (u32)(131071 - gidx);

        // ---- wave reduce (max of packed, first-max tiebreak) ----
#pragma unroll
        for (int off = 32; off; off >>= 1) {
            const u64 o = __shfl_xor(packed, off);
            if (o > packed) packed = o;
        }

        const int par = it & 1;
        if (lane == 0) s_red[par][wv] = packed;   // parity-buffered: no cross-round overwrite
        __syncthreads();                          // the ONLY barrier per round

        if (wv == 0 && lane == 0) {
            u64 blk = s_red[par][0];
            if (s_red[par][1] > blk) blk = s_red[par][1];
            if (s_red[par][2] > blk) blk = s_red[par][2];
            if (s_red[par][3] > blk) blk = s_red[par][3];
            st_agent(slots + par * SUBS + sub, blk);
        }

        // ---- all 4 waves poll the 16 slots independently; per-lane coord
        //      fetch overlaps straggler waiting (x read-only -> cached safe) ----
        u64   v  = 0;
        float wx = 0.0f, wy = 0.0f, wz = 0.0f;
        bool  fresh = (lane >= SUBS);
        u64*  const sp = slots + par * SUBS + lane;
        __builtin_amdgcn_s_sleep(8);              // ~512cy: land check#1 after visibility
        for (;;) {
            if (!fresh) {
                v = ld_agent(sp);
                if ((u32)(v >> 49) == (u32)it) {
                    fresh = true;
                    const int ci = 131071 - (int)(v & 0x1FFFF);
                    wx = xb[3 * ci + 0];          // issued as soon as THIS slot is
                    wy = xb[3 * ci + 1];          // fresh; flies while others poll
                    wz = xb[3 * ci + 2];
                }
            }
            if (__all((int)fresh)) break;
            __builtin_amdgcn_s_sleep(2);          // back off ~128cy between re-checks
        }
        // ---- reduce metas over lanes 0..15 (offsets 8..1 stay in-group) ----
#pragma unroll
        for (int off = 8; off; off >>= 1) {
            const u64 o = __shfl_xor(v, off);
            if (o > v) v = o;
        }
        const u64 win  = __shfl(v, 0);
        const int widx = 131071 - (int)(win & 0x1FFFF);
        const int wsub = widx >> 13;              // owning block (8192-pt chunks)
        cpx = __shfl(wx, wsub);                   // winner's coords already fetched
        cpy = __shfl(wy, wsub);                   //   by lane wsub during the poll
        cpz = __shfl(wz, wsub);
        if (sub == 0 && wv == 0 && lane == 0) {
            float* yo = y + ((size_t)batch * NSAMP + it) * 3;
            yo[0] = cpx; yo[1] = cpy; yo[2] = cpz;
        }
    }
}

extern "C" void kernel_launch(void* const* d_in, const int* in_sizes, int n_in,
                              void* d_out, int out_size, void* d_ws, size_t ws_size,
                              hipStream_t stream) {
    const float* x = (const float*)d_in[0];
    float* y       = (float*)d_out;
    u64* ws        = (u64*)d_ws;   // 16 batches * 1024B = 16 KiB

    // zero all slot words every call (in-graph). Tags used are 1..1023; stale
    // content (zeros, 0xAA poison, previous replay's tags overwritten here)
    // can never spuriously satisfy a round's tag check.
    hipMemsetAsync(d_ws, 0, (size_t)(NBATCH * 1024), stream);

    void* args[] = { (void*)&x, (void*)&y, (void*)&ws };
    hipLaunchCooperativeKernel((void*)fps_kernel,
                               dim3(NBATCH * SUBS), dim3(THREADS),
                               args, 0, stream);
}

// Round 17
// 1921.815 us; speedup vs baseline: 1.0583x; 1.0551x over previous
//
#include <hip/hip_runtime.h>
#include <stdint.h>

typedef unsigned long long u64;
typedef unsigned int u32;

#define NPTS    131072
#define NBATCH  16
#define NSAMP   1024
#define SUBS    16                 // blocks per batch
#define THREADS 256
#define PPT     32                 // points per thread
#define DET_TAG 1023u              // agent parity-0 slots only see even tags 2..1022 in the loop
#define CAP     64                 // fast polls before PERMANENT sticky fallback to agent line

// Packed word: [ tag:10 (bits 49..58) | key:32 (17..48) | (131071-idx):17 (0..16) ]
// key = 0 for masked-out (cand == -1), else float_bits(val)+1 (monotone for val >= 0).
// Max of packed (same tag) == reference first-max argmax (smaller index wins ties).
//
// r17 = r16 with the compile fix: s_sleep takes CONSTANT args only (r16's
// data-dependent args failed the build -- which also retro-explains r3/r4's
// "all-zeros" signatures as silent build failures).
//
// XCD-CLAIMED batch assignment: with grid=256=#CUs (cooperative, 1 block/CU),
// each XCD hosts ~32 blocks regardless of dispatch order. Blocks claim
// (batch,sub) from per-XCD counters -> all 16 subs of a batch share an XCD by
// construction -> sc0 (L1-bypass, XCD-L2-serviced) transport is actually
// exercised for the first time. Spill path for unequal population: vacancy
// scan via presence + release/acquire claim table (rare, correct). Per-batch
// XCC handshake verifies before enabling sc0; CAP-sticky agent fallback
// (r8-proven deadlock-free) guarantees degradation to r9 behavior.
//
// ws layout: per-batch 1024B regions (fast slots u64[0..31], agent slots
// u64[64..95]; det on agent parity-0); claim area at +16KB (u32):
// [0..15]=xcd counters, [16]=spill counter, [32..287]=presence, [288..543]=claimtab.

__device__ __forceinline__ u64 ld_agent(const u64* p) {
    return __hip_atomic_load(p, __ATOMIC_RELAXED, __HIP_MEMORY_SCOPE_AGENT);
}
__device__ __forceinline__ void st_agent(u64* p, u64 v) {
    __hip_atomic_store(p, v, __ATOMIC_RELAXED, __HIP_MEMORY_SCOPE_AGENT);
}
// sc0-only ops: bypass L1, serviced at the issuing XCD's L2 — the coherence
// point for same-XCD blocks. Correctness never depends on them (CAP fallback).
__device__ __forceinline__ u64 ld_sc0(const u64* p) {
    u64 v;
    asm volatile("global_load_dwordx2 %0, %1, off sc0" : "=v"(v) : "v"(p));
    asm volatile("s_waitcnt vmcnt(0)" : "+v"(v) :: "memory");
    return v;
}
__device__ __forceinline__ void st_sc0(u64* p, u64 v) {
    asm volatile("global_store_dwordx2 %0, %1, off sc0" :: "v"(p), "v"(v) : "memory");
}

__global__ __launch_bounds__(THREADS, 1)
void fps_kernel(const float* __restrict__ x, float* __restrict__ y, u64* __restrict__ ws)
{
    const int bid  = blockIdx.x;
    const int tid  = threadIdx.x;
    const int lane = tid & 63;
    const int wv   = tid >> 6;

    u32* const claim = (u32*)(ws + 16 * 128);   // +16KB
    __shared__ u32 s_bs;

    // ---- phase 0: claim (batch,sub) by resident XCD ----
    if (tid == 0) {
        const u32 xcc = (u32)__builtin_amdgcn_s_getreg((31 << 11) | 20) & 0xFu;
        int b = -1, s = 0;
        if (xcc < 8u) {
            const u32 c = __hip_atomic_fetch_add(&claim[xcc], 1u, __ATOMIC_RELAXED,
                                                 __HIP_MEMORY_SCOPE_AGENT);
            if (c < 32u) { b = 2 * (int)xcc + (int)(c >> 4); s = (int)(c & 15u); }
        }
        if (b >= 0) {
            const u32 slot = (u32)(b * SUBS + s);
            __hip_atomic_store(&claim[32 + slot], 1u, __ATOMIC_RELAXED,
                               __HIP_MEMORY_SCOPE_AGENT);
            __hip_atomic_store(&claim[288 + bid], 0x80000000u | slot, __ATOMIC_RELEASE,
                               __HIP_MEMORY_SCOPE_AGENT);
        } else {
            // spill (rare): rank among spills, publish marker, take rank-th vacancy
            const u32 sp = __hip_atomic_fetch_add(&claim[16], 1u, __ATOMIC_RELAXED,
                                                  __HIP_MEMORY_SCOPE_AGENT);
            __hip_atomic_store(&claim[288 + bid], 0x40000000u, __ATOMIC_RELEASE,
                               __HIP_MEMORY_SCOPE_AGENT);
            for (int i = 0; i < 256; ++i)
                while (__hip_atomic_load(&claim[288 + i], __ATOMIC_ACQUIRE,
                                         __HIP_MEMORY_SCOPE_AGENT) == 0u)
                    __builtin_amdgcn_s_sleep(2);
            u32 seen = 0, slot = 0;
            for (u32 q = 0; q < 256; ++q) {
                if (__hip_atomic_load(&claim[32 + q], __ATOMIC_RELAXED,
                                      __HIP_MEMORY_SCOPE_AGENT) == 0u) {
                    if (seen == sp) { slot = q; break; }
                    ++seen;
                }
            }
            b = (int)(slot >> 4); s = (int)(slot & 15u);
        }
        s_bs = ((u32)b << 8) | (u32)s;
    }
    __syncthreads();
    const int batch = (int)(s_bs >> 8);
    const int sub   = (int)(s_bs & 255u);

    const float* __restrict__ xb = x + (size_t)batch * (NPTS * 3);
    const int gbase = sub * 8192 + wv * 2048;

    // ---- load register-resident points + init temps (static indexing only) ----
    float px_[PPT], py_[PPT], pz_[PPT], t_[PPT];
#pragma unroll
    for (int k = 0; k < PPT; ++k) {
        const int g = gbase + k * 64 + lane;
        const float a = xb[3 * g + 0];
        const float b = xb[3 * g + 1];
        const float c = xb[3 * g + 2];
        px_[k] = a; py_[k] = b; pz_[k] = c;
        // exactly as reference: ((a*a + b*b) + c*c), no FMA contraction
        const float mag = __fadd_rn(__fadd_rn(__fmul_rn(a, a), __fmul_rn(b, b)), __fmul_rn(c, c));
        t_[k] = (mag > 1e-3f) ? 1e10f : -1.0f;   // masked-out: cand == -1 forever
    }

    __shared__ u64 s_red[2][4];

    u64* const fastS  = ws + (size_t)batch * 128;   // sc0-only lines
    u64* const agentS = fastS + 64;                 // agent-only lines (+det)

    // ---- per-batch same-XCD handshake (r8 code; det on agent parity-0) ----
    const u32 xcc = (u32)__builtin_amdgcn_s_getreg((31 << 11) | 20) & 0xFu;
    if (tid == 0) st_agent(agentS + sub, ((u64)DET_TAG << 49) | xcc);
    u64 dv;
    {
        const u64* sp = agentS + (lane & 15);
        do { dv = ld_agent(sp); } while ((u32)(dv >> 49) != DET_TAG);
    }
    const bool fast = __all((int)(dv == __shfl(dv, 0)));

    float cpx = xb[0], cpy = xb[1], cpz = xb[2];   // first pick is always index 0
    if (sub == 0 && tid == 0) {
        float* yo = y + (size_t)batch * (NSAMP * 3);
        yo[0] = cpx; yo[1] = cpy; yo[2] = cpz;
    }

    bool agent_only = !fast;   // sticky, wave-uniform

    for (int it = 1; it < NSAMP; ++it) {
        // ---- update temps against current point, thread-local argmax ----
        float bv = -2.0f;
        int   bk = 0;
#pragma unroll
        for (int k = 0; k < PPT; ++k) {
            const float dx = __fsub_rn(px_[k], cpx);
            const float dy = __fsub_rn(py_[k], cpy);
            const float dz = __fsub_rn(pz_[k], cpz);
            const float d  = __fadd_rn(__fadd_rn(__fmul_rn(dx, dx), __fmul_rn(dy, dy)),
                                       __fmul_rn(dz, dz));
            const float tn = fminf(t_[k], d);
            t_[k] = tn;
            if (tn > bv) { bv = tn; bk = k; }   // strict > keeps smallest k
        }
        const int gidx = gbase + bk * 64 + lane;
        const u32 key  = (bv < 0.0f) ? 0u : (__float_as_uint(bv) + 1u);
        u64 packed = ((u64)(u32)it << 49) | ((u64)key << 17) | (u32)(131071 - gidx);

        // ---- wave reduce (max of packed, first-max tiebreak) ----
#pragma unroll
        for (int off = 32; off; off >>= 1) {
            const u64 o = __shfl_xor(packed, off);
            if (o > packed) packed = o;
        }

        const int par = it & 1;
        if (lane == 0) s_red[par][wv] = packed;   // parity-buffered: no cross-round overwrite
        __syncthreads();                          // the ONLY barrier per round

        if (wv == 0 && lane == 0) {
            u64 blk = s_red[par][0];
            if (s_red[par][1] > blk) blk = s_red[par][1];
            if (s_red[par][2] > blk) blk = s_red[par][2];
            if (s_red[par][3] > blk) blk = s_red[par][3];
            if (fast) st_sc0(fastS + par * SUBS + sub, blk);  // same-XCD L2 line
            st_agent(agentS + par * SUBS + sub, blk);         // always: fallback copy
        }

        // ---- all 4 waves poll; per-lane coord fetch overlaps stragglers ----
        u64   v  = 0;
        float wx = 0.0f, wy = 0.0f, wz = 0.0f;
        bool  fresh = (lane >= SUBS);
        bool  use_agent = agent_only;
        u64*  const spF = fastS  + par * SUBS + lane;
        u64*  const spA = agentS + par * SUBS + lane;
        int   tries = 0;
        if (use_agent) { __builtin_amdgcn_s_sleep(8); }   // HBM-class visibility
        else           { __builtin_amdgcn_s_sleep(2); }   // L2 visibility is earlier
        for (;;) {
            if (!fresh) {
                v = use_agent ? ld_agent(spA) : ld_sc0(spF);
                if ((u32)(v >> 49) == (u32)it) {
                    fresh = true;
                    const int ci = 131071 - (int)(v & 0x1FFFF);
                    wx = xb[3 * ci + 0];          // issued as soon as THIS slot is
                    wy = xb[3 * ci + 1];          // fresh; flies while others poll
                    wz = xb[3 * ci + 2];
                }
            }
            if (__all((int)fresh)) break;
            if (!use_agent && ++tries >= CAP) use_agent = true;  // wave-uniform flip
            if (use_agent) { __builtin_amdgcn_s_sleep(2); }
            else           { __builtin_amdgcn_s_sleep(1); }
        }
        agent_only = use_agent;                   // sticky across rounds
        // ---- reduce metas over lanes 0..15 (offsets 8..1 stay in-group) ----
#pragma unroll
        for (int off = 8; off; off >>= 1) {
            const u64 o = __shfl_xor(v, off);
            if (o > v) v = o;
        }
        const u64 win  = __shfl(v, 0);
        const int widx = 131071 - (int)(win & 0x1FFFF);
        const int wsub = widx >> 13;              // owning block (8192-pt chunks)
        cpx = __shfl(wx, wsub);                   // winner's coords already fetched
        cpy = __shfl(wy, wsub);                   //   by lane wsub during the poll
        cpz = __shfl(wz, wsub);
        if (sub == 0 && wv == 0 && lane == 0) {
            float* yo = y + ((size_t)batch * NSAMP + it) * 3;
            yo[0] = cpx; yo[1] = cpy; yo[2] = cpz;
        }
    }
}

extern "C" void kernel_launch(void* const* d_in, const int* in_sizes, int n_in,
                              void* d_out, int out_size, void* d_ws, size_t ws_size,
                              hipStream_t stream) {
    const float* x = (const float*)d_in[0];
    float* y       = (float*)d_out;
    u64* ws        = (u64*)d_ws;   // 16KB batch regions + ~2.2KB claim area

    // zero batch regions + claim area every call (in-graph). Tags are 1..1023
    // (+DET_TAG on agent parity-0 only); zeros/poison/stale can never match.
    // Kernel-dispatch acquire invalidates per-XCD L2s, so no cross-replay
    // sc0 staleness (r8 ran this exact sc0 machinery across replays, passed).
    hipMemsetAsync(d_ws, 0, (size_t)(20 * 1024), stream);

    void* args[] = { (void*)&x, (void*)&y, (void*)&ws };
    hipLaunchCooperativeKernel((void*)fps_kernel,
                               dim3(NBATCH * SUBS), dim3(THREADS),
                               args, 0, stream);
}